// Round 2
// baseline (427.276 us; speedup 1.0000x reference)
//
#include <hip/hip_runtime.h>

typedef unsigned short u16;
typedef unsigned int u32;
typedef __attribute__((ext_vector_type(8))) short short8;   // 8 bf16 = one MFMA A/B frag
typedef __attribute__((ext_vector_type(4))) float f32x4;    // MFMA C/D frag

__device__ __forceinline__ float bf2f(u16 u){
  union { u32 i; float f; } x; x.i = ((u32)u) << 16; return x.f;
}
__device__ __forceinline__ u16 f2bf(float f){
  union { float f; u32 i; } x; x.f = f;
  u32 r = x.i + 0x7fffu + ((x.i >> 16) & 1u);   // round-to-nearest-even
  return (u16)(r >> 16);
}
__device__ __forceinline__ u32 pack2(float a, float b){
  return (u32)f2bf(a) | ((u32)f2bf(b) << 16);
}

// q (bf16, 64 elems) . r (f32, 64 elems)
__device__ __forceinline__ float dot64(const u16* __restrict__ qp, const float* __restrict__ rp){
  float s = 0.f;
  #pragma unroll
  for (int c = 0; c < 64; c += 8) {
    short8 qv = *(const short8*)(qp + c);
    f32x4 rA = *(const f32x4*)(rp + c);
    f32x4 rB = *(const f32x4*)(rp + c + 4);
    s += bf2f((u16)qv[0]) * rA[0] + bf2f((u16)qv[1]) * rA[1]
       + bf2f((u16)qv[2]) * rA[2] + bf2f((u16)qv[3]) * rA[3]
       + bf2f((u16)qv[4]) * rB[0] + bf2f((u16)qv[5]) * rB[1]
       + bf2f((u16)qv[6]) * rB[2] + bf2f((u16)qv[7]) * rB[3];
  }
  return s;
}

// ------------------------------------------------------------------
// cast f32 -> bf16 (n multiple of 4)
// ------------------------------------------------------------------
__global__ void cast_kernel(const float* __restrict__ src, u16* __restrict__ dst, int n){
  int i = (blockIdx.x * blockDim.x + threadIdx.x) * 4;
  if (i >= n) return;
  f32x4 v = *(const f32x4*)(src + i);
  *(u32*)(dst + i)     = pack2(v[0], v[1]);
  *(u32*)(dst + i + 2) = pack2(v[2], v[3]);
}

// ------------------------------------------------------------------
// 128x128-tile GEMM, K=768, stride 768 for A and B. C[m][n] = sum_k A[m][k]*B[n][k] + bias[n]
// AF32: A is f32 (converted during staging). QKV: scatter epilogue into q/k/v bufs.
// ------------------------------------------------------------------
template<bool AF32, bool QKV>
__global__ __launch_bounds__(256) void gemm_k768(
    const void* __restrict__ Ap, const u16* __restrict__ Bp,
    const float* __restrict__ bias,
    void* __restrict__ o0, u16* __restrict__ ok, u16* __restrict__ ov)
{
  __shared__ u16 As[128][40];   // +8 pad
  __shared__ u16 Bs[128][40];
  const int bm0 = blockIdx.x * 128, bn0 = blockIdx.y * 128;
  const int tid = threadIdx.x, lane = tid & 63, wave = tid >> 6;
  const int g = lane >> 4, m16 = lane & 15;
  const int wr = wave >> 1, wc = wave & 1;

  f32x4 acc[4][4];
  #pragma unroll
  for (int i = 0; i < 4; ++i)
    #pragma unroll
    for (int j = 0; j < 4; ++j) acc[i][j] = (f32x4){0.f, 0.f, 0.f, 0.f};

  const int br = tid >> 1, bh8 = (tid & 1) * 16;   // bf16 staging: row, 16-elem half-row

  for (int k0 = 0; k0 < 768; k0 += 32) {
    __syncthreads();
    if constexpr (AF32) {
      const float* A = (const float*)Ap;
      #pragma unroll
      for (int p = 0; p < 2; ++p) {
        int slot = tid + p * 256;
        int r = slot >> 2, c8 = (slot & 3) * 8;
        const float* src = A + (size_t)(bm0 + r) * 768 + k0 + c8;
        f32x4 a0 = *(const f32x4*)src;
        f32x4 a1 = *(const f32x4*)(src + 4);
        u32* d = (u32*)&As[r][c8];
        d[0] = pack2(a0[0], a0[1]); d[1] = pack2(a0[2], a0[3]);
        d[2] = pack2(a1[0], a1[1]); d[3] = pack2(a1[2], a1[3]);
      }
    } else {
      const u16* A = (const u16*)Ap;
      const u16* src = A + (size_t)(bm0 + br) * 768 + k0 + bh8;
      *(short8*)&As[br][bh8]     = *(const short8*)src;        // FIX: stage all 16 elems
      *(short8*)&As[br][bh8 + 8] = *(const short8*)(src + 8);
    }
    const u16* bsrc = Bp + (size_t)(bn0 + br) * 768 + k0 + bh8;
    *(short8*)&Bs[br][bh8]     = *(const short8*)bsrc;         // FIX: stage all 16 elems
    *(short8*)&Bs[br][bh8 + 8] = *(const short8*)(bsrc + 8);
    __syncthreads();

    short8 af[4], bf[4];
    #pragma unroll
    for (int i = 0; i < 4; ++i) {
      af[i] = *(const short8*)&As[wr * 64 + i * 16 + m16][g * 8];
      bf[i] = *(const short8*)&Bs[wc * 64 + i * 16 + m16][g * 8];
    }
    #pragma unroll
    for (int i = 0; i < 4; ++i)
      #pragma unroll
      for (int j = 0; j < 4; ++j)
        acc[i][j] = __builtin_amdgcn_mfma_f32_16x16x32_bf16(af[i], bf[j], acc[i][j], 0, 0, 0);
  }

  #pragma unroll
  for (int i = 0; i < 4; ++i) {
    #pragma unroll
    for (int j = 0; j < 4; ++j) {
      int n = bn0 + wc * 64 + j * 16 + m16;
      float bs = bias[n];
      #pragma unroll
      for (int r = 0; r < 4; ++r) {
        int m = bm0 + wr * 64 + i * 16 + g * 4 + r;
        float v = acc[i][j][r] + bs;
        if constexpr (QKV) {
          int b = m / 2304, t = m - b * 2304;
          int which = n / 768, rem = n - which * 768;
          int h = rem >> 6, d = rem & 63;
          u16* dst = which == 0 ? (u16*)o0 : (which == 1 ? ok : ov);
          dst[(size_t)((b * 12 + h) * 2304 + t) * 64 + d] = f2bf(v);
        } else {
          ((float*)o0)[(size_t)m * 768 + n] = v;
        }
      }
    }
  }
}

// ------------------------------------------------------------------
// v [bh][2304][64] -> vT [bh][64][2304]
// ------------------------------------------------------------------
__global__ __launch_bounds__(256) void vtrans(const u16* __restrict__ v, u16* __restrict__ vT){
  const int bh = blockIdx.y, t0 = blockIdx.x * 64;
  __shared__ u16 Tl[64][66];
  const int tid = threadIdx.x;
  #pragma unroll
  for (int p = 0; p < 2; ++p) {
    int slot = tid + p * 256;
    int r = slot >> 3, c0 = (slot & 7) * 8;
    short8 val = *(const short8*)(v + (size_t)(bh * 2304 + t0 + r) * 64 + c0);
    #pragma unroll
    for (int j = 0; j < 8; ++j) Tl[c0 + j][r] = (u16)val[j];   // Tl[d][t]
  }
  __syncthreads();
  #pragma unroll
  for (int p = 0; p < 2; ++p) {
    int slot = tid + p * 256;
    int d = slot >> 3, c0 = (slot & 7) * 8;
    short8 o;
    #pragma unroll
    for (int j = 0; j < 8; ++j) o[j] = (short)Tl[d][c0 + j];
    *(short8*)(vT + ((size_t)bh * 64 + d) * 2304 + t0 + c0) = o;
  }
}

// ------------------------------------------------------------------
// Fused attention. Block = (qh, bh): 48 q-rows (shared qh), 3 waves x 16 rows.
// logits = 0.125*(q.k) + RelH[q_local][kh] + RelW[q_local][kw]  (both tables f32, prologue).
// Swapped QK^T: S^T[k][q] via mfma(K, Q^T); softmax per-lane; P via wave-private LDS -> PV.
// ------------------------------------------------------------------
#define LOG2E 1.4426950408889634f

__global__ __launch_bounds__(192) void attn_fused(
    const u16* __restrict__ qbuf, const u16* __restrict__ kbuf, const u16* __restrict__ vTbuf,
    const float* __restrict__ rph, const float* __restrict__ rpw, u16* __restrict__ aout)
{
  const int qh = blockIdx.x;   // 0..47
  const int bh = blockIdx.y;   // 0..23
  const int tid = threadIdx.x;
  const int wave = tid >> 6, lane = tid & 63;
  const int g = lane >> 4, m16 = lane & 15;

  __shared__ u16  Kt[64][72];       // K tile [k][c], 144B rows (conflict-free b128)
  __shared__ u16  Vt[64][72];       // V^T tile [d][k]
  __shared__ float RelW[48][49];    // q[ql] . rel_pos_w[ql-kw+47]
  __shared__ float RelH[48][49];    // q[ql] . rel_pos_h[qh-kh+47]
  __shared__ u16  Plds[3][16][72];  // per-wave P [q][k]

  const int tok0 = qh * 48;
  const u16* qrow = qbuf + (size_t)(bh * 2304 + tok0) * 64;

  // ---- prologue: f32 rel-pos tables ----
  for (int idx = tid; idx < 48 * 48; idx += 192) {
    int ql = idx / 48, kw = idx - ql * 48;
    RelW[ql][kw] = dot64(qrow + ql * 64, rpw + (ql - kw + 47) * 64);
  }
  for (int idx = tid; idx < 48 * 48; idx += 192) {
    int ql = idx / 48, kh = idx - ql * 48;
    RelH[ql][kh] = dot64(qrow + ql * 64, rph + (qh - kh + 47) * 64);
  }

  // ---- Q fragments (B-operand of swapped QK^T), unscaled ----
  const int qloc = wave * 16 + m16;
  short8 qf0 = *(const short8*)(qrow + qloc * 64 + g * 8);
  short8 qf1 = *(const short8*)(qrow + qloc * 64 + 32 + g * 8);

  f32x4 o[4];
  #pragma unroll
  for (int t = 0; t < 4; ++t) o[t] = (f32x4){0.f, 0.f, 0.f, 0.f};
  float mrun = -1e30f, lrun = 0.f;

  for (int kt = 0; kt < 36; ++kt) {
    const int k0 = kt * 64;
    const int kh0 = k0 / 48, kw0 = k0 - kh0 * 48;   // kw0 in {0,16,32}
    __syncthreads();   // protect Kt/Vt reads of previous tile (covers RelW/RelH on kt==0)
    // ---- stage K and V^T (pure copies) ----
    for (int slot = tid; slot < 512; slot += 192) {
      const int kr = slot >> 3, c0 = (slot & 7) * 8;
      *(short8*)&Kt[kr][c0] = *(const short8*)(kbuf + (size_t)(bh * 2304 + k0 + kr) * 64 + c0);
      *(short8*)&Vt[kr][c0] = *(const short8*)(vTbuf + ((size_t)bh * 64 + kr) * 2304 + k0 + c0);
    }
    __syncthreads();

    // ---- S^T[k][q] = K . Q^T ----
    f32x4 st[4];
    #pragma unroll
    for (int mt = 0; mt < 4; ++mt) st[mt] = (f32x4){0.f, 0.f, 0.f, 0.f};
    #pragma unroll
    for (int mt = 0; mt < 4; ++mt) {
      short8 a0 = *(const short8*)&Kt[mt * 16 + m16][g * 8];
      st[mt] = __builtin_amdgcn_mfma_f32_16x16x32_bf16(a0, qf0, st[mt], 0, 0, 0);
    }
    #pragma unroll
    for (int mt = 0; mt < 4; ++mt) {
      short8 a1 = *(const short8*)&Kt[mt * 16 + m16][32 + g * 8];
      st[mt] = __builtin_amdgcn_mfma_f32_16x16x32_bf16(a1, qf1, st[mt], 0, 0, 0);
    }

    // ---- online softmax (per-lane column q = qloc) ----
    float p[16];
    float tmax = -1e30f;
    #pragma unroll
    for (int mt = 0; mt < 4; ++mt)
      #pragma unroll
      for (int r = 0; r < 4; ++r) {
        int s_ = kw0 + mt * 16 + g * 4 + r;          // <= 95
        int kw = s_ >= 48 ? s_ - 48 : s_;
        int kh = s_ >= 48 ? kh0 + 1 : kh0;
        float lg = st[mt][r] * 0.125f + RelH[qloc][kh] + RelW[qloc][kw];
        p[mt * 4 + r] = lg;
        tmax = fmaxf(tmax, lg);
      }
    tmax = fmaxf(tmax, __shfl_xor(tmax, 16));
    tmax = fmaxf(tmax, __shfl_xor(tmax, 32));
    float mnew = fmaxf(mrun, tmax);
    float alpha = exp2f((mrun - mnew) * LOG2E);
    float tsum = 0.f;
    #pragma unroll
    for (int i = 0; i < 16; ++i) { p[i] = exp2f((p[i] - mnew) * LOG2E); tsum += p[i]; }
    tsum += __shfl_xor(tsum, 16);
    tsum += __shfl_xor(tsum, 32);
    lrun = lrun * alpha + tsum;
    mrun = mnew;
    // rescale O (O rows are q' = 4g+r; alpha lives at lane q'=m16, any g)
    #pragma unroll
    for (int r = 0; r < 4; ++r) {
      float ar = __shfl(alpha, g * 4 + r);
      o[0][r] *= ar; o[1][r] *= ar; o[2][r] *= ar; o[3][r] *= ar;
    }
    // ---- pack P to wave-private LDS [q][k] bf16 ----
    #pragma unroll
    for (int mt = 0; mt < 4; ++mt) {
      *(u32*)&Plds[wave][m16][mt * 16 + g * 4]     = pack2(p[mt * 4 + 0], p[mt * 4 + 1]);
      *(u32*)&Plds[wave][m16][mt * 16 + g * 4 + 2] = pack2(p[mt * 4 + 2], p[mt * 4 + 3]);
    }
    asm volatile("s_waitcnt lgkmcnt(0)" ::: "memory");  // cross-lane RAW within wave
    // ---- PV: O[q][d] += P.V ----
    #pragma unroll
    for (int s = 0; s < 2; ++s) {
      short8 ap = *(const short8*)&Plds[wave][m16][s * 32 + g * 8];
      #pragma unroll
      for (int t = 0; t < 4; ++t) {
        short8 bv = *(const short8*)&Vt[t * 16 + m16][s * 32 + g * 8];
        o[t] = __builtin_amdgcn_mfma_f32_16x16x32_bf16(ap, bv, o[t], 0, 0, 0);
      }
    }
  }

  // ---- epilogue ----
  float inv = 1.0f / lrun;                 // for q = m16
  const int b = bh / 12, h = bh - b * 12;
  #pragma unroll
  for (int r = 0; r < 4; ++r) {
    float ir = __shfl(inv, g * 4 + r);
    int row = b * 2304 + tok0 + wave * 16 + g * 4 + r;
    u16* dst = aout + (size_t)row * 768 + h * 64;
    dst[m16]      = f2bf(o[0][r] * ir);
    dst[16 + m16] = f2bf(o[1][r] * ir);
    dst[32 + m16] = f2bf(o[2][r] * ir);
    dst[48 + m16] = f2bf(o[3][r] * ir);
  }
}

// ------------------------------------------------------------------
extern "C" void kernel_launch(void* const* d_in, const int* in_sizes, int n_in,
                              void* d_out, int out_size, void* d_ws, size_t ws_size,
                              hipStream_t stream)
{
  (void)in_sizes; (void)n_in; (void)out_size; (void)ws_size;
  const float* x     = (const float*)d_in[0];
  const float* qkvw  = (const float*)d_in[1];
  const float* qkvb  = (const float*)d_in[2];
  const float* projw = (const float*)d_in[3];
  const float* projb = (const float*)d_in[4];
  const float* rph   = (const float*)d_in[5];
  const float* rpw   = (const float*)d_in[6];
  float* out = (float*)d_out;

  char* p = (char*)d_ws;
  u16* wqkv  = (u16*)p;  p += (size_t)2304 * 768 * 2;
  u16* wproj = (u16*)p;  p += (size_t)768 * 768 * 2;
  u16* qb    = (u16*)p;  p += (size_t)24 * 2304 * 64 * 2;
  u16* kb    = (u16*)p;  p += (size_t)24 * 2304 * 64 * 2;
  u16* vb    = (u16*)p;  p += (size_t)24 * 2304 * 64 * 2;
  u16* vT    = (u16*)p;  p += (size_t)24 * 64 * 2304 * 2;
  u16* aout  = (u16*)p;  p += (size_t)4608 * 768 * 2;   // ~40 MB total

  cast_kernel<<<dim3(2304 * 768 / 4 / 256), dim3(256), 0, stream>>>(qkvw, wqkv, 2304 * 768);
  cast_kernel<<<dim3(768 * 768 / 4 / 256), dim3(256), 0, stream>>>(projw, wproj, 768 * 768);
  gemm_k768<true, true><<<dim3(36, 18), dim3(256), 0, stream>>>(x, wqkv, qkvb, qb, kb, vb);
  vtrans<<<dim3(36, 24), dim3(256), 0, stream>>>(vb, vT);
  attn_fused<<<dim3(48, 24), dim3(192), 0, stream>>>(qb, kb, vT, rph, rpw, aout);
  gemm_k768<false, false><<<dim3(36, 6), dim3(256), 0, stream>>>(aout, wproj, projb, out, nullptr, nullptr);
}

// Round 3
// 240.161 us; speedup vs baseline: 1.7791x; 1.7791x over previous
//
#include <hip/hip_runtime.h>

typedef unsigned short u16;
typedef unsigned int u32;
typedef __attribute__((ext_vector_type(8))) short short8;   // 8 bf16 = MFMA A/B frag
typedef __attribute__((ext_vector_type(4))) float f32x4;
typedef __attribute__((ext_vector_type(16))) float f32x16;
typedef __attribute__((ext_vector_type(2))) unsigned int u32x2;

__device__ __forceinline__ float bf2f(u16 u){
  union { u32 i; float f; } x; x.i = ((u32)u) << 16; return x.f;
}
__device__ __forceinline__ u16 f2bf(float f){
  union { float f; u32 i; } x; x.f = f;
  u32 r = x.i + 0x7fffu + ((x.i >> 16) & 1u);   // RNE
  return (u16)(r >> 16);
}
__device__ __forceinline__ u32 pack2(float a, float b){
  return (u32)f2bf(a) | ((u32)f2bf(b) << 16);
}
__device__ __forceinline__ u32 cvtpk(float a, float b){
  u32 r; asm("v_cvt_pk_bf16_f32 %0, %1, %2" : "=v"(r) : "v"(a), "v"(b)); return r;
}
__device__ __forceinline__ float bf_lo(u32 w){
  union { u32 i; float f; } x; x.i = w << 16; return x.f;
}
__device__ __forceinline__ float bf_hi(u32 w){
  union { u32 i; float f; } x; x.i = w & 0xffff0000u; return x.f;
}
__device__ __forceinline__ f32x16 mfma32(short8 a, short8 b, f32x16 c){
  return __builtin_amdgcn_mfma_f32_32x32x16_bf16(a, b, c, 0, 0, 0);
}

// ------------------------------------------------------------------
__global__ void cast_kernel(const float* __restrict__ src, u16* __restrict__ dst, int n){
  int i = (blockIdx.x * blockDim.x + threadIdx.x) * 4;
  if (i >= n) return;
  f32x4 v = *(const f32x4*)(src + i);
  *(u32*)(dst + i)     = pack2(v[0], v[1]);
  *(u32*)(dst + i + 2) = pack2(v[2], v[3]);
}

// ------------------------------------------------------------------
// 128x128-tile GEMM, K=768. C[m][n] = sum_k A[m][k]*B[n][k] + bias[n]
// ------------------------------------------------------------------
template<bool AF32, bool QKV>
__global__ __launch_bounds__(256) void gemm_k768(
    const void* __restrict__ Ap, const u16* __restrict__ Bp,
    const float* __restrict__ bias,
    void* __restrict__ o0, u16* __restrict__ ok, u16* __restrict__ ov)
{
  __shared__ u16 As[128][40];
  __shared__ u16 Bs[128][40];
  const int bm0 = blockIdx.x * 128, bn0 = blockIdx.y * 128;
  const int tid = threadIdx.x, lane = tid & 63, wave = tid >> 6;
  const int g = lane >> 4, m16 = lane & 15;
  const int wr = wave >> 1, wc = wave & 1;

  f32x4 acc[4][4];
  #pragma unroll
  for (int i = 0; i < 4; ++i)
    #pragma unroll
    for (int j = 0; j < 4; ++j) acc[i][j] = (f32x4){0.f, 0.f, 0.f, 0.f};

  const int br = tid >> 1, bh8 = (tid & 1) * 16;

  for (int k0 = 0; k0 < 768; k0 += 32) {
    __syncthreads();
    if constexpr (AF32) {
      const float* A = (const float*)Ap;
      #pragma unroll
      for (int p = 0; p < 2; ++p) {
        int slot = tid + p * 256;
        int r = slot >> 2, c8 = (slot & 3) * 8;
        const float* src = A + (size_t)(bm0 + r) * 768 + k0 + c8;
        f32x4 a0 = *(const f32x4*)src;
        f32x4 a1 = *(const f32x4*)(src + 4);
        u32* d = (u32*)&As[r][c8];
        d[0] = pack2(a0[0], a0[1]); d[1] = pack2(a0[2], a0[3]);
        d[2] = pack2(a1[0], a1[1]); d[3] = pack2(a1[2], a1[3]);
      }
    } else {
      const u16* A = (const u16*)Ap;
      const u16* src = A + (size_t)(bm0 + br) * 768 + k0 + bh8;
      *(short8*)&As[br][bh8]     = *(const short8*)src;
      *(short8*)&As[br][bh8 + 8] = *(const short8*)(src + 8);
    }
    const u16* bsrc = Bp + (size_t)(bn0 + br) * 768 + k0 + bh8;
    *(short8*)&Bs[br][bh8]     = *(const short8*)bsrc;
    *(short8*)&Bs[br][bh8 + 8] = *(const short8*)(bsrc + 8);
    __syncthreads();

    short8 af[4], bf[4];
    #pragma unroll
    for (int i = 0; i < 4; ++i) {
      af[i] = *(const short8*)&As[wr * 64 + i * 16 + m16][g * 8];
      bf[i] = *(const short8*)&Bs[wc * 64 + i * 16 + m16][g * 8];
    }
    #pragma unroll
    for (int i = 0; i < 4; ++i)
      #pragma unroll
      for (int j = 0; j < 4; ++j)
        acc[i][j] = __builtin_amdgcn_mfma_f32_16x16x32_bf16(af[i], bf[j], acc[i][j], 0, 0, 0);
  }

  #pragma unroll
  for (int i = 0; i < 4; ++i) {
    #pragma unroll
    for (int j = 0; j < 4; ++j) {
      int n = bn0 + wc * 64 + j * 16 + m16;
      float bs = bias[n];
      #pragma unroll
      for (int r = 0; r < 4; ++r) {
        int m = bm0 + wr * 64 + i * 16 + g * 4 + r;
        float v = acc[i][j][r] + bs;
        if constexpr (QKV) {
          int b = m / 2304, t = m - b * 2304;
          int which = n / 768, rem = n - which * 768;
          int hh = rem >> 6, d = rem & 63;
          u16* dst = which == 0 ? (u16*)o0 : (which == 1 ? ok : ov);
          dst[(size_t)((b * 12 + hh) * 2304 + t) * 64 + d] = f2bf(v);
        } else {
          ((float*)o0)[(size_t)m * 768 + n] = v;
        }
      }
    }
  }
}

// ------------------------------------------------------------------
// v [bh][2304][64] -> vT [bh][64][2304]
// ------------------------------------------------------------------
__global__ __launch_bounds__(256) void vtrans(const u16* __restrict__ v, u16* __restrict__ vT){
  const int bh = blockIdx.y, t0 = blockIdx.x * 64;
  __shared__ u16 Tl[64][66];
  const int tid = threadIdx.x;
  #pragma unroll
  for (int p = 0; p < 2; ++p) {
    int slot = tid + p * 256;
    int r = slot >> 3, c0 = (slot & 7) * 8;
    short8 val = *(const short8*)(v + (size_t)(bh * 2304 + t0 + r) * 64 + c0);
    #pragma unroll
    for (int j = 0; j < 8; ++j) Tl[c0 + j][r] = (u16)val[j];
  }
  __syncthreads();
  #pragma unroll
  for (int p = 0; p < 2; ++p) {
    int slot = tid + p * 256;
    int d = slot >> 3, c0 = (slot & 7) * 8;
    short8 o;
    #pragma unroll
    for (int j = 0; j < 8; ++j) o[j] = (short)Tl[d][c0 + j];
    *(short8*)(vT + ((size_t)bh * 64 + d) * 2304 + t0 + c0) = o;
  }
}

// ------------------------------------------------------------------
// Barrier-free fused attention, 32x32x16 MFMA, 32 q-rows per wave.
// Block = 96 q-rows (2 qh groups) x one bh; 3 waves. Tables RelH/RelW built
// by MFMA prologue (pre-scaled by LOG2E, bf16 in LDS). Swapped QK^T makes
// softmax fully lane-local; defer-max skips rescale on almost all tiles;
// PV B-frag assembled from lane-local P + one lane^32 exchange.
// ------------------------------------------------------------------
#define LOG2E 1.4426950408889634f
#define SSC   0.18033688011f      /* 0.125 * LOG2E */

__global__ __launch_bounds__(192, 3) void attn_fused32(
    const u16* __restrict__ qbuf, const u16* __restrict__ kbuf, const u16* __restrict__ vTbuf,
    const u16* __restrict__ rphb, const u16* __restrict__ rpwb, u16* __restrict__ aout)
{
  // XCD-chunked swizzle: 576 = 8 * 72; 72 blocks = 3 full bh per XCD
  int flat = blockIdx.x;
  flat = (flat & 7) * 72 + (flat >> 3);
  const int bh = flat / 24, qb = flat - bh * 24;
  const int q0 = qb * 96;
  const int qh0 = qb * 2;

  const int tid = threadIdx.x, wave = tid >> 6, lane = tid & 63;
  const int l31 = lane & 31, h = lane >> 5;
  const int m16 = lane & 15, g = lane >> 4;

  __shared__ u16 RelH[96][52];      // bf16, pre-scaled by LOG2E
  __shared__ u16 RelW[96][52];
  __shared__ u16 Olds[3][32][72];   // per-wave epilogue transpose buffer

  const size_t bhq = (size_t)bh * 2304;

  // ---- prologue: bias tables via 16x16x32 MFMA GEMM + scatter ----
  // wave w computes rows ql = 32w .. 32w+31 (its OWN rows)
  #pragma unroll
  for (int half = 0; half < 2; ++half) {
    const int it = wave * 2 + half;
    const u16* qap = qbuf + (bhq + q0 + it * 16 + m16) * 64;
    short8 qa0 = *(const short8*)(qap + g * 8);
    short8 qa1 = *(const short8*)(qap + 32 + g * 8);
    #pragma unroll
    for (int tb = 0; tb < 2; ++tb) {
      const u16* rt = tb ? rpwb : rphb;
      u16* tbl = tb ? &RelW[0][0] : &RelH[0][0];
      for (int jt = 0; jt < 6; ++jt) {
        f32x4 c = {0.f, 0.f, 0.f, 0.f};
        const u16* bp = rt + (jt * 16 + m16) * 64;
        short8 b0 = *(const short8*)(bp + g * 8);
        short8 b1 = *(const short8*)(bp + 32 + g * 8);
        c = __builtin_amdgcn_mfma_f32_16x16x32_bf16(qa0, b0, c, 0, 0, 0);
        c = __builtin_amdgcn_mfma_f32_16x16x32_bf16(qa1, b1, c, 0, 0, 0);
        const int j = jt * 16 + m16;
        #pragma unroll
        for (int r = 0; r < 4; ++r) {
          const int ql = it * 16 + g * 4 + r;
          const int base = tb ? (ql >= 48 ? ql - 48 : ql) : (qh0 + (ql >= 48 ? 1 : 0));
          const int kidx = base - j + 47;
          if (kidx >= 0 && kidx < 48) tbl[ql * 52 + kidx] = f2bf(c[r] * LOG2E);
        }
      }
    }
  }
  __syncthreads();

  // ---- persistent Q B-frags: Q[qrow][dc*16 + h*8 + e] ----
  const int qloc = wave * 32 + l31;
  const u16* qrp = qbuf + (bhq + q0 + qloc) * 64;
  short8 qf0 = *(const short8*)(qrp + h * 8);
  short8 qf1 = *(const short8*)(qrp + 16 + h * 8);
  short8 qf2 = *(const short8*)(qrp + 32 + h * 8);
  short8 qf3 = *(const short8*)(qrp + 48 + h * 8);

  f32x16 oA, oB;
  #pragma unroll
  for (int i = 0; i < 16; ++i) { oA[i] = 0.f; oB[i] = 0.f; }
  float mrun = -1e30f;
  float lr0 = 0.f, lr1 = 0.f, lr2 = 0.f, lr3 = 0.f;
  const u16* kbase = kbuf + bhq * 64;
  const u16* vbase = vTbuf + (size_t)bh * 64 * 2304;

  for (int kt = 0; kt < 36; ++kt) {
    const int k0 = kt * 64;
    const int kh0 = (kt * 4) / 3;            // k0 / 48
    const int rem0 = k0 - kh0 * 48;          // in {0,16,32}

    // bias reads (independent, issue early)
    float rh0 = bf2f(RelH[qloc][kh0]);
    float rh1 = bf2f(RelH[qloc][kh0 + 1]);
    u32x2 rw[8];
    float rhg[8];
    #pragma unroll
    for (int ta = 0; ta < 8; ++ta) {         // ta = t*4 + a; group of 4 consecutive k
      const int s0 = rem0 + (ta >> 2) * 32 + (ta & 3) * 8 + h * 4;
      const int kwb = s0 >= 48 ? s0 - 48 : s0;   // multiple of 4 -> b64 aligned
      rhg[ta] = s0 >= 48 ? rh1 : rh0;
      rw[ta] = *(const u32x2*)&RelW[qloc][kwb];
    }

    // ---- QK^T: S^T[64k][32q], A = K rows, B = Q^T ----
    f32x16 st0, st1;
    #pragma unroll
    for (int i = 0; i < 16; ++i) { st0[i] = 0.f; st1[i] = 0.f; }
    #pragma unroll
    for (int dc = 0; dc < 4; ++dc) {
      short8 ka0 = *(const short8*)(kbase + (size_t)(k0 + l31) * 64 + dc * 16 + h * 8);
      short8 ka1 = *(const short8*)(kbase + (size_t)(k0 + 32 + l31) * 64 + dc * 16 + h * 8);
      short8 qfc = dc == 0 ? qf0 : dc == 1 ? qf1 : dc == 2 ? qf2 : qf3;
      st0 = mfma32(ka0, qfc, st0);
      st1 = mfma32(ka1, qfc, st1);
    }

    // ---- logits in place + per-lane tmax ----
    float tmax = -1e30f;
    #pragma unroll
    for (int t = 0; t < 2; ++t) {
      f32x16& stt = t ? st1 : st0;
      #pragma unroll
      for (int a = 0; a < 4; ++a) {
        const int ta = t * 4 + a;
        const float b0 = rhg[ta] + bf_lo(rw[ta].x);
        const float b1 = rhg[ta] + bf_hi(rw[ta].x);
        const float b2 = rhg[ta] + bf_lo(rw[ta].y);
        const float b3 = rhg[ta] + bf_hi(rw[ta].y);
        stt[a * 4 + 0] = fmaf(stt[a * 4 + 0], SSC, b0);
        stt[a * 4 + 1] = fmaf(stt[a * 4 + 1], SSC, b1);
        stt[a * 4 + 2] = fmaf(stt[a * 4 + 2], SSC, b2);
        stt[a * 4 + 3] = fmaf(stt[a * 4 + 3], SSC, b3);
        tmax = fmaxf(tmax, fmaxf(fmaxf(stt[a * 4 + 0], stt[a * 4 + 1]),
                                 fmaxf(stt[a * 4 + 2], stt[a * 4 + 3])));
      }
    }

    // ---- defer-max online softmax (log2 domain) ----
    if (__any(tmax > mrun + 8.f)) {
      float tm = fmaxf(tmax, __shfl_xor(tmax, 32));
      float mnew = fmaxf(mrun, tm);
      float al = exp2f(mrun - mnew);
      #pragma unroll
      for (int i = 0; i < 16; ++i) { oA[i] *= al; oB[i] *= al; }
      lr0 *= al; lr1 *= al; lr2 *= al; lr3 *= al;
      mrun = mnew;
    }
    #pragma unroll
    for (int i = 0; i < 16; ++i) {
      st0[i] = exp2f(st0[i] - mrun);
      st1[i] = exp2f(st1[i] - mrun);
    }
    #pragma unroll
    for (int i = 0; i < 4; ++i) {
      lr0 += st0[4 * i + 0] + st1[4 * i + 0];
      lr1 += st0[4 * i + 1] + st1[4 * i + 1];
      lr2 += st0[4 * i + 2] + st1[4 * i + 2];
      lr3 += st0[4 * i + 3] + st1[4 * i + 3];
    }

    // ---- pack P -> bf16, lane^32 exchange, PV ----
    #pragma unroll
    for (int j = 0; j < 4; ++j) {
      f32x16& stt = (j >> 1) ? st1 : st0;
      const int a0 = (j & 1) * 2;
      u32 A00 = cvtpk(stt[a0 * 4 + 0], stt[a0 * 4 + 1]);
      u32 A01 = cvtpk(stt[a0 * 4 + 2], stt[a0 * 4 + 3]);
      u32 A10 = cvtpk(stt[a0 * 4 + 4], stt[a0 * 4 + 5]);
      u32 A11 = cvtpk(stt[a0 * 4 + 6], stt[a0 * 4 + 7]);
      u32 sx0 = __shfl_xor(A00, 32), sx1 = __shfl_xor(A01, 32);
      u32 sy0 = __shfl_xor(A10, 32), sy1 = __shfl_xor(A11, 32);
      short8 pb;
      u32* pw = (u32*)&pb;
      pw[0] = h ? sy0 : A00;
      pw[1] = h ? sy1 : A01;
      pw[2] = h ? A10 : sx0;
      pw[3] = h ? A11 : sx1;
      short8 va  = *(const short8*)(vbase + (size_t)l31 * 2304 + k0 + j * 16 + h * 8);
      short8 vb_ = *(const short8*)(vbase + (size_t)(32 + l31) * 2304 + k0 + j * 16 + h * 8);
      oA = mfma32(va, pb, oA);
      oB = mfma32(vb_, pb, oB);
    }
  }

  // ---- epilogue: normalize, transpose via per-wave LDS, coalesced store ----
  float lrt = lr0 + lr1 + lr2 + lr3;
  lrt += __shfl_xor(lrt, 32);
  const float inv = 1.0f / lrt;
  #pragma unroll
  for (int dt = 0; dt < 2; ++dt) {
    const f32x16& oo = dt ? oB : oA;
    #pragma unroll
    for (int rp = 0; rp < 8; ++rp) {
      u32 w = cvtpk(oo[2 * rp] * inv, oo[2 * rp + 1] * inv);
      const int d = 32 * dt + 2 * (rp & 1) + 8 * (rp >> 1) + 4 * h;
      *(u32*)&Olds[wave][l31][d] = w;
    }
  }
  asm volatile("s_waitcnt lgkmcnt(0)" ::: "memory");
  const int b = bh / 12, head = bh - b * 12;
  u16* dst = aout + ((size_t)b * 2304 + q0 + wave * 32 + l31) * 768 + head * 64 + h * 32;
  #pragma unroll
  for (int j = 0; j < 4; ++j)
    *(short8*)(dst + j * 8) = *(const short8*)&Olds[wave][l31][h * 32 + j * 8];
}

// ------------------------------------------------------------------
extern "C" void kernel_launch(void* const* d_in, const int* in_sizes, int n_in,
                              void* d_out, int out_size, void* d_ws, size_t ws_size,
                              hipStream_t stream)
{
  (void)in_sizes; (void)n_in; (void)out_size; (void)ws_size;
  const float* x     = (const float*)d_in[0];
  const float* qkvw  = (const float*)d_in[1];
  const float* qkvb  = (const float*)d_in[2];
  const float* projw = (const float*)d_in[3];
  const float* projb = (const float*)d_in[4];
  const float* rph   = (const float*)d_in[5];
  const float* rpw   = (const float*)d_in[6];
  float* out = (float*)d_out;

  char* p = (char*)d_ws;
  u16* wqkv  = (u16*)p;  p += (size_t)2304 * 768 * 2;
  u16* wproj = (u16*)p;  p += (size_t)768 * 768 * 2;
  u16* rphb  = (u16*)p;  p += (size_t)95 * 64 * 2;
  u16* rpwb  = (u16*)p;  p += (size_t)95 * 64 * 2;
  u16* qb    = (u16*)p;  p += (size_t)24 * 2304 * 64 * 2;
  u16* kb    = (u16*)p;  p += (size_t)24 * 2304 * 64 * 2;
  u16* vb    = (u16*)p;  p += (size_t)24 * 2304 * 64 * 2;
  u16* vT    = (u16*)p;  p += (size_t)24 * 64 * 2304 * 2;
  u16* aout  = (u16*)p;  p += (size_t)4608 * 768 * 2;

  cast_kernel<<<dim3(2304 * 768 / 4 / 256), dim3(256), 0, stream>>>(qkvw, wqkv, 2304 * 768);
  cast_kernel<<<dim3(768 * 768 / 4 / 256), dim3(256), 0, stream>>>(projw, wproj, 768 * 768);
  cast_kernel<<<dim3(6), dim3(256), 0, stream>>>(rph, rphb, 95 * 64);
  cast_kernel<<<dim3(6), dim3(256), 0, stream>>>(rpw, rpwb, 95 * 64);
  gemm_k768<true, true><<<dim3(36, 18), dim3(256), 0, stream>>>(x, wqkv, qkvb, qb, kb, vb);
  vtrans<<<dim3(36, 24), dim3(256), 0, stream>>>(vb, vT);
  attn_fused32<<<dim3(576), dim3(192), 0, stream>>>(qb, kb, vT, rphb, rpwb, aout);
  gemm_k768<false, false><<<dim3(36, 6), dim3(256), 0, stream>>>(aout, wproj, projb, out, nullptr, nullptr);
}